// Round 3
// baseline (3000.108 us; speedup 1.0000x reference)
//
#include <hip/hip_runtime.h>
#include <hip/hip_bf16.h>

// TemporalAttention: B=8,T=128,N=64,K=8 heads,d=64,D=512
// H=[X|STE] [65536,1536] -> q,k,v = relu(H @ W^T + b) [65536,512] each
// per (head,b,n): S=q k^T/8, causal mask, softmax, O=P v
// out = relu(O @ Wo^T + bo)
// Round 3: ALL I/O is fp32 (reference dtype). Internals bf16:
// fp32 -> bf16 conversion in GEMM staging; qkv/att workspace bf16;
// final GEMM writes fp32 to d_out. Attention stays plain-VALU (one
// variable per round; rounds 1-2 failed on the dtype misread:
// NaN accumulators -> final ReLU -> exact-zero output == stub error).

typedef __attribute__((ext_vector_type(8))) short short8;     // 8 x bf16 frag
typedef __attribute__((ext_vector_type(4))) float floatx4;    // MFMA acc / 16B fp32 ld
typedef __attribute__((ext_vector_type(4))) unsigned int uintx4; // 16B ld/st

static __device__ __forceinline__ ushort f2b(float f) {
  __hip_bfloat16 h = __float2bfloat16(f);
  return __builtin_bit_cast(ushort, h);
}
// exact bf16 -> fp32 unpack from a packed uint (2 bf16)
static __device__ __forceinline__ float blo(unsigned int w) {
  return __builtin_bit_cast(float, w << 16);
}
static __device__ __forceinline__ float bhi(unsigned int w) {
  return __builtin_bit_cast(float, w & 0xffff0000u);
}
// load 8 consecutive fp32, convert to 8 packed bf16 (2 x dwordx4 loads)
static __device__ __forceinline__ uintx4 cvt8(const float* __restrict__ p) {
  const floatx4 f0 = *(const floatx4*)(p);
  const floatx4 f1 = *(const floatx4*)(p + 4);
  uintx4 r;
  r[0] = (unsigned int)f2b(f0[0]) | ((unsigned int)f2b(f0[1]) << 16);
  r[1] = (unsigned int)f2b(f0[2]) | ((unsigned int)f2b(f0[3]) << 16);
  r[2] = (unsigned int)f2b(f1[0]) | ((unsigned int)f2b(f1[1]) << 16);
  r[3] = (unsigned int)f2b(f1[2]) | ((unsigned int)f2b(f1[3]) << 16);
  return r;
}

// ---------------------------------------------------------------------------
// C[m, cbase+o] = relu(sum_c A[m,c] * W[o,c] + bias[o]),  A,W K-contiguous.
// A: fp32 (A_BF16=false, optionally CONCAT [X ld512 | STE ld1024]) or bf16 ws.
// W,bias: fp32 always. Output: fp32 (OUT_F32) or bf16 ws.
// TRIPLE: n-tiles 0..11 map to {Wq,Wk,Wv} x 4 tiles of 128; ldc=1536.
// 128x128 tile, BK=64, 4 waves, each wave 4x4 tiles of 16x16x32 bf16 MFMA.
// ---------------------------------------------------------------------------
template<int KDIM, bool CONCAT, bool TRIPLE, bool A_BF16, bool OUT_F32>
__global__ __launch_bounds__(256, 2)
void gemm_relu_bt(const void* __restrict__ A0v, const void* __restrict__ A1v,
                  const float* __restrict__ W0, const float* __restrict__ W1,
                  const float* __restrict__ W2,
                  const float* __restrict__ bias0, const float* __restrict__ bias1,
                  const float* __restrict__ bias2,
                  void* __restrict__ Cv, int ldc)
{
  __shared__ ushort As[128 * 72];   // stride 72 bf16 = 144 B (16B aligned)
  __shared__ ushort Bs[128 * 72];

  const int tn = blockIdx.x, tm = blockIdx.y;
  const int tid = threadIdx.x;
  const int wave = tid >> 6, lane = tid & 63;
  const int quad = lane >> 4, lid = lane & 15;
  const int wm = wave >> 1, wn = wave & 1;

  const float* W; const float* bias; int nbase, cbase;
  if (TRIPLE) {
    const int seg = tn >> 2;
    W    = (seg == 0) ? W0 : (seg == 1) ? W1 : W2;
    bias = (seg == 0) ? bias0 : (seg == 1) ? bias1 : bias2;
    nbase = (tn & 3) * 128;
    cbase = seg * 512;
  } else { W = W0; bias = bias0; nbase = tn * 128; cbase = 0; }

  floatx4 acc[4][4];
#pragma unroll
  for (int i = 0; i < 4; i++)
#pragma unroll
    for (int j = 0; j < 4; j++) acc[i][j] = (floatx4){0.f, 0.f, 0.f, 0.f};

  for (int kt = 0; kt < KDIM / 64; ++kt) {
    // ---- stage A,B tiles: 128 rows x 64 cols (8-elem chunks), 4 chunks/thread
#pragma unroll
    for (int i = 0; i < 4; i++) {
      const int cidx = tid + i * 256;
      const int row = cidx >> 3, ch = cidx & 7;
      const int k0 = kt * 64 + ch * 8;
      uintx4 va, vb;
      if (A_BF16) {
        const ushort* A0 = (const ushort*)A0v;
        va = *(const uintx4*)(A0 + (size_t)(tm * 128 + row) * KDIM + k0);
      } else if (CONCAT) {
        const int m = tm * 128 + row;
        if (k0 < 512) va = cvt8((const float*)A0v + (size_t)m * 512 + k0);
        else          va = cvt8((const float*)A1v + (size_t)m * 1024 + (k0 - 512));
      } else {
        va = cvt8((const float*)A0v + (size_t)(tm * 128 + row) * KDIM + k0);
      }
      vb = cvt8(W + (size_t)(nbase + row) * KDIM + k0);
      *(uintx4*)(&As[row * 72 + ch * 8]) = va;
      *(uintx4*)(&Bs[row * 72 + ch * 8]) = vb;
    }
    __syncthreads();
    // ---- 2 k-steps of 32, 16 MFMAs each
#pragma unroll
    for (int ks = 0; ks < 2; ++ks) {
      short8 af[4], bfr[4];
#pragma unroll
      for (int t = 0; t < 4; t++) {
        af[t]  = *(const short8*)(&As[(wm * 64 + t * 16 + lid) * 72 + ks * 32 + quad * 8]);
        bfr[t] = *(const short8*)(&Bs[(wn * 64 + t * 16 + lid) * 72 + ks * 32 + quad * 8]);
      }
#pragma unroll
      for (int i = 0; i < 4; i++)
#pragma unroll
        for (int j = 0; j < 4; j++)
          acc[i][j] = __builtin_amdgcn_mfma_f32_16x16x32_bf16(af[i], bfr[j], acc[i][j], 0, 0, 0);
    }
    __syncthreads();
  }

  // ---- epilogue: C row = quad*4+reg, col = lane&15 (verified m89/m91 layout)
#pragma unroll
  for (int j = 0; j < 4; j++) {
    const int ncol = nbase + wn * 64 + j * 16 + lid;
    const float bv = bias[ncol];
    const int cg = cbase + ncol;
#pragma unroll
    for (int i = 0; i < 4; i++) {
      const int mrow = tm * 128 + wm * 64 + i * 16 + quad * 4;
#pragma unroll
      for (int r = 0; r < 4; r++) {
        float v = acc[i][j][r] + bv;
        v = v > 0.f ? v : 0.f;
        if (OUT_F32) ((float*)Cv)[(size_t)(mrow + r) * ldc + cg] = v;
        else         ((ushort*)Cv)[(size_t)(mrow + r) * ldc + cg] = f2b(v);
      }
    }
  }
}

// ---------------------------------------------------------------------------
// Plain-VALU attention, one block per (head,b,n), one thread per row t.
// qkv workspace is bf16. Two-pass fp32 softmax over s<=t (masked cols
// excluded; matches reference NEG-mask semantics since exp underflows).
// ---------------------------------------------------------------------------
__global__ void attn_valu(const ushort* __restrict__ qkv, ushort* __restrict__ outb)
{
  __shared__ ushort qs_[128 * 64];   // 16 KB
  __shared__ ushort ks_[128 * 64];   // 16 KB
  __shared__ ushort vs_[128 * 64];   // 16 KB

  const int bx = blockIdx.x;
  const int head = bx >> 9;
  const int b = (bx >> 6) & 7;
  const int n = bx & 63;
  const int t = threadIdx.x;         // 0..127, one row per thread

  // ---- stage q,k,v rows for this (b,n,head): thread t loads row t (16B loads)
  {
    const ushort* base = qkv + ((size_t)((b * 128 + t) * 64 + n)) * 1536 + head * 64;
#pragma unroll
    for (int c = 0; c < 8; c++) {
      *(uintx4*)(&qs_[t * 64 + c * 8]) = *(const uintx4*)(base + c * 8);
      *(uintx4*)(&ks_[t * 64 + c * 8]) = *(const uintx4*)(base + 512 + c * 8);
      *(uintx4*)(&vs_[t * 64 + c * 8]) = *(const uintx4*)(base + 1024 + c * 8);
    }
  }
  __syncthreads();

  // ---- unpack my q row to fp32
  float q[64];
#pragma unroll
  for (int c = 0; c < 8; c++) {
    const uintx4 qw = *(const uintx4*)(&qs_[t * 64 + c * 8]);
#pragma unroll
    for (int j = 0; j < 4; j++) {
      q[c * 8 + 2 * j]     = blo(qw[j]);
      q[c * 8 + 2 * j + 1] = bhi(qw[j]);
    }
  }

  // ---- pass 1: row max of S[t, 0..t]
  float mx = -3.4e38f;
  for (int s = 0; s <= t; s++) {
    float dot = 0.f;
#pragma unroll
    for (int c = 0; c < 8; c++) {
      const uintx4 kw = *(const uintx4*)(&ks_[s * 64 + c * 8]);
#pragma unroll
      for (int j = 0; j < 4; j++) {
        dot += q[c * 8 + 2 * j] * blo(kw[j]);
        dot += q[c * 8 + 2 * j + 1] * bhi(kw[j]);
      }
    }
    mx = fmaxf(mx, dot * 0.125f);
  }

  // ---- pass 2: p = exp(S - mx), accumulate sum and O = sum_s p * v[s]
  float out[64];
#pragma unroll
  for (int d0 = 0; d0 < 64; d0++) out[d0] = 0.f;
  float sum = 0.f;
  for (int s = 0; s <= t; s++) {
    float dot = 0.f;
#pragma unroll
    for (int c = 0; c < 8; c++) {
      const uintx4 kw = *(const uintx4*)(&ks_[s * 64 + c * 8]);
#pragma unroll
      for (int j = 0; j < 4; j++) {
        dot += q[c * 8 + 2 * j] * blo(kw[j]);
        dot += q[c * 8 + 2 * j + 1] * bhi(kw[j]);
      }
    }
    const float p = __expf(dot * 0.125f - mx);
    sum += p;
#pragma unroll
    for (int c = 0; c < 8; c++) {
      const uintx4 vw = *(const uintx4*)(&vs_[s * 64 + c * 8]);
#pragma unroll
      for (int j = 0; j < 4; j++) {
        out[c * 8 + 2 * j]     += p * blo(vw[j]);
        out[c * 8 + 2 * j + 1] += p * bhi(vw[j]);
      }
    }
  }

  // ---- write O[t][dd] -> att[((b*128+t)*64+n)*512 + head*64 + dd] (bf16 ws)
  const float inv = 1.f / sum;
  ushort* ob = outb + ((size_t)((b * 128 + t) * 64 + n)) * 512 + head * 64;
#pragma unroll
  for (int d0 = 0; d0 < 64; d0++) ob[d0] = f2b(out[d0] * inv);
}

extern "C" void kernel_launch(void* const* d_in, const int* in_sizes, int n_in,
                              void* d_out, int out_size, void* d_ws, size_t ws_size,
                              hipStream_t stream) {
  const float* X   = (const float*)d_in[0];   // [8,128,64,512]   fp32
  const float* STE = (const float*)d_in[1];   // [8,128,64,1024]  fp32
  const float* Wq  = (const float*)d_in[2];   // [512,1536]       fp32
  const float* bq  = (const float*)d_in[3];
  const float* Wk  = (const float*)d_in[4];
  const float* bk  = (const float*)d_in[5];
  const float* Wv  = (const float*)d_in[6];
  const float* bv  = (const float*)d_in[7];
  const float* Wo  = (const float*)d_in[8];   // [512,512]        fp32
  const float* bo  = (const float*)d_in[9];
  float* out = (float*)d_out;                 // [8,128,64,512]   fp32

  ushort* qkv = (ushort*)d_ws;                       // [65536,1536] bf16, 201 MB
  ushort* att = qkv + (size_t)65536 * 1536;          // [65536,512]  bf16, 67 MB

  // 1) fused QKV projection + ReLU (fp32 in, bf16 ws out)
  gemm_relu_bt<1536, true, true, false, false><<<dim3(12, 512), 256, 0, stream>>>(
      X, STE, Wq, Wk, Wv, bq, bk, bv, qkv, 1536);
  // 2) causal attention per (head,b,n) — plain VALU version (bf16 ws in/out)
  attn_valu<<<dim3(4096), 128, 0, stream>>>(qkv, att);
  // 3) output projection + ReLU (bf16 ws in, fp32 out)
  gemm_relu_bt<512, false, false, true, true><<<dim3(4, 512), 256, 0, stream>>>(
      att, nullptr, Wo, nullptr, nullptr, bo, nullptr, nullptr, out, 512);
}